// Round 1
// baseline (8512.795 us; speedup 1.0000x reference)
//
#include <hip/hip_runtime.h>
#include <cmath>

#define B_    2
#define S_    2048
#define H_    4096
#define NH_   32
#define NKV_  8
#define D_    128
#define G_    4
#define QKV_N ((NH_ + 2 * NKV_) * D_)   // 6144
#define MTOK  (B_ * S_)                  // 4096

// ---------------- fp32 SGEMM: 128x128 tile, BK=8, 8x8 per thread ----------------
__global__ __launch_bounds__(256) void sgemm_kernel(const float* __restrict__ A,
                                                    const float* __restrict__ Bm,
                                                    float* __restrict__ C,
                                                    int M, int N, int K) {
  __shared__ float As[8][128];   // transposed A tile: As[k][m]
  __shared__ float Bs[8][128];   // Bs[k][n]
  const int tid = threadIdx.x;
  const int bm = blockIdx.y, bn = blockIdx.x;
  const int tx = tid & 15, ty = tid >> 4;
  // staging indices: A tile is 128 rows x 8 k-cols; B tile 8 k-rows x 128 cols
  const int ar = tid >> 1, ac = (tid & 1) * 4;
  const int br = tid >> 5, bc = (tid & 31) * 4;
  const float* Aptr = A + (size_t)(bm * 128 + ar) * K + ac;
  const float* Bptr = Bm + (size_t)br * N + bn * 128 + bc;

  float acc[8][8];
#pragma unroll
  for (int i = 0; i < 8; ++i)
#pragma unroll
    for (int j = 0; j < 8; ++j) acc[i][j] = 0.f;

  for (int k0 = 0; k0 < K; k0 += 8) {
    float4 a4 = *(const float4*)(Aptr + k0);
    float4 b4 = *(const float4*)(Bptr + (size_t)k0 * N);
    __syncthreads();
    As[ac + 0][ar] = a4.x;
    As[ac + 1][ar] = a4.y;
    As[ac + 2][ar] = a4.z;
    As[ac + 3][ar] = a4.w;
    *(float4*)&Bs[br][bc] = b4;
    __syncthreads();
#pragma unroll
    for (int kk = 0; kk < 8; ++kk) {
      float a[8], b[8];
      *(float4*)&a[0] = *(const float4*)&As[kk][ty * 8];
      *(float4*)&a[4] = *(const float4*)&As[kk][ty * 8 + 4];
      *(float4*)&b[0] = *(const float4*)&Bs[kk][tx * 8];
      *(float4*)&b[4] = *(const float4*)&Bs[kk][tx * 8 + 4];
#pragma unroll
      for (int i = 0; i < 8; ++i)
#pragma unroll
        for (int j = 0; j < 8; ++j) acc[i][j] = fmaf(a[i], b[j], acc[i][j]);
    }
  }
  float* Cptr = C + (size_t)(bm * 128 + ty * 8) * N + bn * 128 + tx * 8;
#pragma unroll
  for (int i = 0; i < 8; ++i) {
    *(float4*)(Cptr + (size_t)i * N)     = *(float4*)&acc[i][0];
    *(float4*)(Cptr + (size_t)i * N + 4) = *(float4*)&acc[i][4];
  }
}

// ---------------- RoPE (interleaved), in-place on q & k slices of qkv ----------------
__global__ void rope_kernel(float* __restrict__ qkv, const int* __restrict__ positions) {
  int idx = blockIdx.x * blockDim.x + threadIdx.x;
  // idx -> (tok, head in [0, NH+NKV), pair j in [0,64))
  int j = idx & 63;
  int tmp = idx >> 6;
  int head = tmp % (NH_ + NKV_);
  int tok = tmp / (NH_ + NKV_);
  if (tok >= MTOK) return;
  // inv_freq = theta^(-2j/128); log2(10000) = 13.287712379549449
  float inv = exp2f(-(float)(2 * j) * (13.287712379549449f / 128.f));
  float f = (float)positions[tok] * inv;
  float s, c;
  sincosf(f, &s, &c);
  float* base = qkv + (size_t)tok * QKV_N + head * D_ + 2 * j;
  float x1 = base[0], x2 = base[1];
  base[0] = x1 * c - x2 * s;
  base[1] = x2 * c + x1 * s;
}

// ---------------- fp32 causal GQA flash attention ----------------
// grid: (S/64, NH, B); block 256.  4 threads per q-row, each owns 32 of 128 dims.
__global__ __launch_bounds__(256) void flash_attn_kernel(const float* __restrict__ qkv,
                                                         float* __restrict__ aout) {
  __shared__ float Ks[64][128];
  __shared__ float Vs[64][128];
  const int qt = blockIdx.x, h = blockIdx.y, b = blockIdx.z;
  const int kvh = h >> 2;  // G = 4
  const int tid = threadIdx.x;
  const int qr = tid >> 2, seg = tid & 3;
  const int qrow = qt * 64 + qr;

  const float* qptr = qkv + (size_t)(b * S_ + qrow) * QKV_N + h * D_ + seg * 32;
  float qv[32];
#pragma unroll
  for (int i = 0; i < 32; i += 4) *(float4*)&qv[i] = *(const float4*)(qptr + i);

  float m = -1e30f, l = 0.f;
  float oacc[32];
#pragma unroll
  for (int i = 0; i < 32; ++i) oacc[i] = 0.f;

  const int nkt = qt + 1;
  for (int kt = 0; kt < nkt; ++kt) {
    __syncthreads();
#pragma unroll
    for (int i = 0; i < 8; ++i) {
      int li = tid + i * 256;           // 0..2047 -> 64 rows x 32 float4
      int r = li >> 5, c = (li & 31) * 4;
      const float* kp = qkv + (size_t)(b * S_ + kt * 64 + r) * QKV_N + NH_ * D_ + kvh * D_ + c;
      *(float4*)&Ks[r][c] = *(const float4*)kp;
      *(float4*)&Vs[r][c] = *(const float4*)(kp + NKV_ * D_);
    }
    __syncthreads();
    const bool diag = (kt == qt);
#pragma unroll 1
    for (int ch = 0; ch < 2; ++ch) {
      float sc[32];
#pragma unroll
      for (int kk = 0; kk < 32; ++kk) {
        int key = ch * 32 + kk;
        float d = 0.f;
        const float4* kr = (const float4*)&Ks[key][seg * 32];
#pragma unroll
        for (int i4 = 0; i4 < 8; ++i4) {
          float4 k4 = kr[i4];
          d = fmaf(qv[i4 * 4 + 0], k4.x, d);
          d = fmaf(qv[i4 * 4 + 1], k4.y, d);
          d = fmaf(qv[i4 * 4 + 2], k4.z, d);
          d = fmaf(qv[i4 * 4 + 3], k4.w, d);
        }
        d += __shfl_xor(d, 1);
        d += __shfl_xor(d, 2);
        d *= 0.08838834764831845f;     // 1/sqrt(128)
        if (diag && key > qr) d = -1e30f;
        sc[kk] = d;
      }
      float cmax = sc[0];
#pragma unroll
      for (int kk = 1; kk < 32; ++kk) cmax = fmaxf(cmax, sc[kk]);
      float mn = fmaxf(m, cmax);
      float alpha = __expf(m - mn);
      m = mn;
      l *= alpha;
#pragma unroll
      for (int i = 0; i < 32; ++i) oacc[i] *= alpha;
      float psum = 0.f;
#pragma unroll
      for (int kk = 0; kk < 32; ++kk) {
        float p = __expf(sc[kk] - mn);
        psum += p;
        const float4* vr = (const float4*)&Vs[ch * 32 + kk][seg * 32];
#pragma unroll
        for (int i4 = 0; i4 < 8; ++i4) {
          float4 v4 = vr[i4];
          oacc[i4 * 4 + 0] = fmaf(p, v4.x, oacc[i4 * 4 + 0]);
          oacc[i4 * 4 + 1] = fmaf(p, v4.y, oacc[i4 * 4 + 1]);
          oacc[i4 * 4 + 2] = fmaf(p, v4.z, oacc[i4 * 4 + 2]);
          oacc[i4 * 4 + 3] = fmaf(p, v4.w, oacc[i4 * 4 + 3]);
        }
      }
      l += psum;
    }
  }
  float inv_l = 1.f / l;
  float* op = aout + (size_t)(b * S_ + qrow) * (NH_ * D_) + h * D_ + seg * 32;
#pragma unroll
  for (int i4 = 0; i4 < 8; ++i4) {
    float4 o4;
    o4.x = oacc[i4 * 4 + 0] * inv_l;
    o4.y = oacc[i4 * 4 + 1] * inv_l;
    o4.z = oacc[i4 * 4 + 2] * inv_l;
    o4.w = oacc[i4 * 4 + 3] * inv_l;
    *(float4*)(op + i4 * 4) = o4;
  }
}

extern "C" void kernel_launch(void* const* d_in, const int* in_sizes, int n_in,
                              void* d_out, int out_size, void* d_ws, size_t ws_size,
                              hipStream_t stream) {
  const float* hs    = (const float*)d_in[0];
  const int*   pos   = (const int*)d_in[1];
  const float* w_qkv = (const float*)d_in[2];
  const float* w_o   = (const float*)d_in[3];
  float* out = (float*)d_out;

  float* qkv  = (float*)d_ws;                       // MTOK x 6144
  float* aout = qkv + (size_t)MTOK * QKV_N;         // MTOK x 4096

  // 1) qkv = hs @ w_qkv   (M=4096, N=6144, K=4096)
  dim3 g1(QKV_N / 128, MTOK / 128);
  sgemm_kernel<<<g1, 256, 0, stream>>>(hs, w_qkv, qkv, MTOK, QKV_N, H_);

  // 2) RoPE on q and k heads
  int total = MTOK * (NH_ + NKV_) * (D_ / 2);
  rope_kernel<<<total / 256, 256, 0, stream>>>(qkv, pos);

  // 3) causal GQA flash attention
  dim3 ga(S_ / 64, NH_, B_);
  flash_attn_kernel<<<ga, 256, 0, stream>>>(qkv, aout);

  // 4) out = aout @ w_o   (M=4096, N=4096, K=4096)
  dim3 g2(H_ / 128, MTOK / 128);
  sgemm_kernel<<<g2, 256, 0, stream>>>(aout, w_o, out, MTOK, H_, NH_ * D_);
}